// Round 1
// baseline (10898.849 us; speedup 1.0000x reference)
//
#include <hip/hip_runtime.h>
#include <math.h>

#define B_ 128
#define P_ 196
#define E_ 2048
#define D_ 512
#define A_ 512
#define M_ 512
#define V_ 10000
#define L_ 21
#define T_ 20

// ---------------------------------------------------------------------------
// order kernel: stable argsort by descending caption length (B=128)
// also builds declen_sorted and the row map for the sorted encoder view
// ---------------------------------------------------------------------------
__global__ void order_kernel(const int* __restrict__ lens, int* __restrict__ order,
                             int* __restrict__ declen, int* __restrict__ row_map) {
  __shared__ int s_order[B_];
  int tid = threadIdx.x;
  if (tid < B_) {
    int li = lens[tid];
    int r = 0;
    for (int j = 0; j < B_; ++j) {
      int lj = lens[j];
      r += (lj > li) || (lj == li && j < tid);
    }
    s_order[r] = tid;
    declen[r] = li - 1;
  }
  __syncthreads();
  if (tid < B_) order[tid] = s_order[tid];
  for (int m = tid; m < B_ * P_; m += blockDim.x) {
    int b = m / P_, p = m - b * P_;
    row_map[m] = s_order[b] * P_ + p;
  }
}

// ---------------------------------------------------------------------------
// mean over P of sorted encoder rows: mean[b,e]
// ---------------------------------------------------------------------------
__global__ void mean_kernel(const float* __restrict__ enc, const int* __restrict__ order,
                            float* __restrict__ mean) {
  int b = blockIdx.y;
  int e = blockIdx.x * blockDim.x + threadIdx.x;
  int ob = order[b];
  const float* base = enc + (long long)ob * P_ * E_ + e;
  float s = 0.f;
  for (int p = 0; p < P_; ++p) s += base[(long long)p * E_];
  mean[b * E_ + e] = s * (1.0f / P_);
}

// ---------------------------------------------------------------------------
// generic fp32 tiled GEMM: C[m,n] = sum_k A[m,k] * B[k,n]   (BT=false, B row-major [K,N])
//                          C[m,n] = sum_k A[m,k] * B[n,k]   (BT=true,  B row-major [N,K])
// 64x64 tile, BK=16, 256 threads, 4x4 per thread.
// optional: row_map indirection on A rows, bias, sigmoid, accumulate, mask+strided C.
// ---------------------------------------------------------------------------
template <bool BT, int ACT, bool ACCUM, bool MASK>
__global__ __launch_bounds__(256) void gemm_kernel(
    const float* __restrict__ A, const float* __restrict__ Bm,
    const float* __restrict__ bias, float* __restrict__ C,
    int M, int N, int K,
    const int* __restrict__ row_map,
    long long c_rstride, long long c_base,
    const int* __restrict__ declen, int t) {
  __shared__ float As[16][64];
  __shared__ float Bs[16][64];
  const int tid = threadIdx.x;
  const int bm = blockIdx.y * 64, bn = blockIdx.x * 64;
  const int tm = tid >> 4, tn = tid & 15;

  float acc[4][4];
#pragma unroll
  for (int i = 0; i < 4; ++i)
#pragma unroll
    for (int j = 0; j < 4; ++j) acc[i][j] = 0.f;

  const int lm = tid >> 2;        // 0..63
  const int lk = (tid & 3) * 4;   // 0,4,8,12

  for (int k0 = 0; k0 < K; k0 += 16) {
    // A tile: 64 rows x 16 k
    {
      int m = bm + lm;
      float4 v = make_float4(0.f, 0.f, 0.f, 0.f);
      if (m < M) {
        int row = row_map ? row_map[m] : m;
        v = *(const float4*)(A + (long long)row * K + k0 + lk);
      }
      As[lk + 0][lm] = v.x;
      As[lk + 1][lm] = v.y;
      As[lk + 2][lm] = v.z;
      As[lk + 3][lm] = v.w;
    }
    // B tile: 16 k x 64 n
    if (!BT) {
      int k = tid >> 4;             // 0..15
      int n4 = (tid & 15) * 4;
      int n = bn + n4;
      float4 v = make_float4(0.f, 0.f, 0.f, 0.f);
      if (n < N) v = *(const float4*)(Bm + (long long)(k0 + k) * N + n);
      Bs[k][n4 + 0] = v.x;
      Bs[k][n4 + 1] = v.y;
      Bs[k][n4 + 2] = v.z;
      Bs[k][n4 + 3] = v.w;
    } else {
      int n = bn + lm;
      float4 v = make_float4(0.f, 0.f, 0.f, 0.f);
      if (n < N) v = *(const float4*)(Bm + (long long)n * K + k0 + lk);
      Bs[lk + 0][lm] = v.x;
      Bs[lk + 1][lm] = v.y;
      Bs[lk + 2][lm] = v.z;
      Bs[lk + 3][lm] = v.w;
    }
    __syncthreads();
#pragma unroll
    for (int k = 0; k < 16; ++k) {
      float a0 = As[k][tm * 4 + 0];
      float a1 = As[k][tm * 4 + 1];
      float a2 = As[k][tm * 4 + 2];
      float a3 = As[k][tm * 4 + 3];
      float b0 = Bs[k][tn * 4 + 0];
      float b1 = Bs[k][tn * 4 + 1];
      float b2 = Bs[k][tn * 4 + 2];
      float b3 = Bs[k][tn * 4 + 3];
      acc[0][0] += a0 * b0; acc[0][1] += a0 * b1; acc[0][2] += a0 * b2; acc[0][3] += a0 * b3;
      acc[1][0] += a1 * b0; acc[1][1] += a1 * b1; acc[1][2] += a1 * b2; acc[1][3] += a1 * b3;
      acc[2][0] += a2 * b0; acc[2][1] += a2 * b1; acc[2][2] += a2 * b2; acc[2][3] += a2 * b3;
      acc[3][0] += a3 * b0; acc[3][1] += a3 * b1; acc[3][2] += a3 * b2; acc[3][3] += a3 * b3;
    }
    __syncthreads();
  }

#pragma unroll
  for (int i = 0; i < 4; ++i) {
    int m = bm + tm * 4 + i;
    if (m >= M) continue;
    bool active = true;
    if (MASK) active = (t < declen[m]);
#pragma unroll
    for (int j = 0; j < 4; ++j) {
      int n = bn + tn * 4 + j;
      if (n >= N) continue;
      float v = acc[i][j];
      if (bias) v += bias[n];
      long long ci = c_base + (long long)m * c_rstride + n;
      if (ACCUM) v += C[ci];
      if (ACT == 1) v = 1.f / (1.f + __expf(-v));
      if (MASK && !active) v = 0.f;
      C[ci] = v;
    }
  }
}

// ---------------------------------------------------------------------------
// fused attention: e = relu(att1 + att2) . w + b ; softmax over P ; write alpha
// (masked) to output ; awe = alpha . enc
// one block per (sorted) batch row, 256 threads
// ---------------------------------------------------------------------------
__global__ __launch_bounds__(256) void attn_kernel(
    const float* __restrict__ att1, const float* __restrict__ att2,
    const float* __restrict__ enc, const int* __restrict__ order,
    const float* __restrict__ w, const float* __restrict__ fb,
    const int* __restrict__ declen, int t,
    float* __restrict__ awe, float* __restrict__ alpha_out) {
  __shared__ float att2_s[A_];
  __shared__ float w_s[A_];
  __shared__ float e_s[P_];
  __shared__ float red[8];
  int b = blockIdx.x, tid = threadIdx.x;
  for (int i = tid; i < A_; i += 256) {
    att2_s[i] = att2[b * A_ + i];
    w_s[i] = w[i];
  }
  __syncthreads();
  int wave = tid >> 6, lane = tid & 63;
  for (int p = wave; p < P_; p += 4) {
    const float* row = att1 + ((long long)b * P_ + p) * A_;
    float s = 0.f;
#pragma unroll
    for (int i = 0; i < A_ / 64; ++i) {
      int idx = lane + i * 64;
      float v = row[idx] + att2_s[idx];
      s += (v > 0.f ? v : 0.f) * w_s[idx];
    }
    for (int off = 32; off; off >>= 1) s += __shfl_down(s, off);
    if (lane == 0) e_s[p] = s + fb[0];
  }
  __syncthreads();
  // softmax over P_ entries
  float m = -1e30f;
  for (int p = tid; p < P_; p += 256) m = fmaxf(m, e_s[p]);
  for (int off = 32; off; off >>= 1) m = fmaxf(m, __shfl_down(m, off));
  if (lane == 0) red[wave] = m;
  __syncthreads();
  m = fmaxf(fmaxf(red[0], red[1]), fmaxf(red[2], red[3]));
  float ssum = 0.f;
  for (int p = tid; p < P_; p += 256) {
    float ev = __expf(e_s[p] - m);
    e_s[p] = ev;
    ssum += ev;
  }
  for (int off = 32; off; off >>= 1) ssum += __shfl_down(ssum, off);
  if (lane == 0) red[4 + wave] = ssum;
  __syncthreads();
  ssum = red[4] + red[5] + red[6] + red[7];
  float inv = 1.f / ssum;
  bool active = (t < declen[b]);
  for (int p = tid; p < P_; p += 256) {
    float al = e_s[p] * inv;
    e_s[p] = al;
    alpha_out[(long long)b * (T_ * P_) + t * P_ + p] = active ? al : 0.f;
  }
  __syncthreads();
  int ob = order[b];
  const float* eb = enc + (long long)ob * P_ * E_;
  for (int e = tid; e < E_; e += 256) {
    float s2 = 0.f;
    for (int p = 0; p < P_; ++p) s2 += e_s[p] * eb[(long long)p * E_ + e];
    awe[b * E_ + e] = s2;
  }
}

// ---------------------------------------------------------------------------
// build x = [embedding(cap_t) , gate * awe]
// ---------------------------------------------------------------------------
__global__ void buildx_kernel(const float* __restrict__ emb, const int* __restrict__ caps,
                              const int* __restrict__ order, const float* __restrict__ gate,
                              const float* __restrict__ awe, float* __restrict__ x, int t) {
  int b = blockIdx.x, tid = threadIdx.x;
  int cap = caps[order[b] * L_ + t];
  for (int j = tid; j < M_; j += 256) x[b * (M_ + E_) + j] = emb[(long long)cap * M_ + j];
  for (int j = tid; j < E_; j += 256)
    x[b * (M_ + E_) + M_ + j] = gate[b * E_ + j] * awe[b * E_ + j];
}

// ---------------------------------------------------------------------------
// LSTM elementwise: gates -> c,h update
// ---------------------------------------------------------------------------
__global__ void lstm_ew_kernel(const float* __restrict__ g, float* __restrict__ h,
                               float* __restrict__ c) {
  int idx = blockIdx.x * blockDim.x + threadIdx.x;  // b*512 + d
  int b = idx >> 9, d = idx & 511;
  const float* gr = g + b * 2048;
  float gi = gr[d], gf = gr[512 + d], gg = gr[1024 + d], go = gr[1536 + d];
  float si = 1.f / (1.f + __expf(-gi));
  float sf = 1.f / (1.f + __expf(-gf));
  float so = 1.f / (1.f + __expf(-go));
  float cn = sf * c[idx] + si * tanhf(gg);
  float hn = so * tanhf(cn);
  c[idx] = cn;
  h[idx] = hn;
}

// ---------------------------------------------------------------------------
// launch
// ---------------------------------------------------------------------------
extern "C" void kernel_launch(void* const* d_in, const int* in_sizes, int n_in,
                              void* d_out, int out_size, void* d_ws, size_t ws_size,
                              hipStream_t stream) {
  const float* enc       = (const float*)d_in[0];
  const int*   caps      = (const int*)d_in[1];
  const int*   lens      = (const int*)d_in[2];
  const float* emb       = (const float*)d_in[3];
  const float* enc_att_w = (const float*)d_in[4];
  const float* enc_att_b = (const float*)d_in[5];
  const float* dec_att_w = (const float*)d_in[6];
  const float* dec_att_b = (const float*)d_in[7];
  const float* full_att_w = (const float*)d_in[8];
  const float* full_att_b = (const float*)d_in[9];
  const float* init_h_w  = (const float*)d_in[10];
  const float* init_h_b  = (const float*)d_in[11];
  const float* init_c_w  = (const float*)d_in[12];
  const float* init_c_b  = (const float*)d_in[13];
  const float* f_beta_w  = (const float*)d_in[14];
  const float* f_beta_b  = (const float*)d_in[15];
  const float* lstm_w_ih = (const float*)d_in[16];
  const float* lstm_b_ih = (const float*)d_in[17];
  const float* lstm_w_hh = (const float*)d_in[18];
  const float* lstm_b_hh = (const float*)d_in[19];
  const float* fc_w      = (const float*)d_in[20];
  const float* fc_b      = (const float*)d_in[21];

  float* out = (float*)d_out;
  float* alphas_out = out + (long long)B_ * T_ * V_;

  // workspace layout (floats, then ints)
  float* ws = (float*)d_ws;
  float* att1 = ws;                               // 25088*512
  float* mean = att1 + (long long)B_ * P_ * A_;   // 128*2048
  float* h    = mean + B_ * E_;                   // 128*512
  float* c    = h + B_ * D_;
  float* att2 = c + B_ * D_;
  float* awe  = att2 + B_ * A_;                   // 128*2048
  float* gate = awe + B_ * E_;                    // 128*2048
  float* x    = gate + B_ * E_;                   // 128*2560
  float* g    = x + B_ * (M_ + E_);               // 128*2048
  int* order  = (int*)(g + B_ * 4 * D_);
  int* declen = order + B_;
  int* row_map = declen + B_;                     // 25088

  // 1. sort
  hipLaunchKernelGGL(order_kernel, dim3(1), dim3(256), 0, stream, lens, order, declen, row_map);
  // 2. mean
  hipLaunchKernelGGL(mean_kernel, dim3(E_ / 256, B_), dim3(256), 0, stream, enc, order, mean);
  // 3/4. h0, c0
  hipLaunchKernelGGL((gemm_kernel<false, 0, false, false>), dim3(D_ / 64, 2), dim3(256), 0, stream,
                     mean, init_h_w, init_h_b, h, B_, D_, E_, (const int*)nullptr,
                     (long long)D_, 0LL, (const int*)nullptr, 0);
  hipLaunchKernelGGL((gemm_kernel<false, 0, false, false>), dim3(D_ / 64, 2), dim3(256), 0, stream,
                     mean, init_c_w, init_c_b, c, B_, D_, E_, (const int*)nullptr,
                     (long long)D_, 0LL, (const int*)nullptr, 0);
  // 5. att1 (the big GEMM)
  hipLaunchKernelGGL((gemm_kernel<false, 0, false, false>), dim3(A_ / 64, (B_ * P_) / 64),
                     dim3(256), 0, stream, enc, enc_att_w, enc_att_b, att1, B_ * P_, A_, E_,
                     row_map, (long long)A_, 0LL, (const int*)nullptr, 0);

  for (int t = 0; t < T_; ++t) {
    // att2 = h @ dec_att_w + b
    hipLaunchKernelGGL((gemm_kernel<false, 0, false, false>), dim3(A_ / 64, 2), dim3(256), 0,
                       stream, h, dec_att_w, dec_att_b, att2, B_, A_, D_, (const int*)nullptr,
                       (long long)A_, 0LL, (const int*)nullptr, 0);
    // gate = sigmoid(h @ f_beta_w + b)
    hipLaunchKernelGGL((gemm_kernel<false, 1, false, false>), dim3(E_ / 64, 2), dim3(256), 0,
                       stream, h, f_beta_w, f_beta_b, gate, B_, E_, D_, (const int*)nullptr,
                       (long long)E_, 0LL, (const int*)nullptr, 0);
    // attention: e/softmax/alpha/awe
    hipLaunchKernelGGL(attn_kernel, dim3(B_), dim3(256), 0, stream, att1, att2, enc, order,
                       full_att_w, full_att_b, declen, t, awe, alphas_out);
    // x = [emb, gate*awe]
    hipLaunchKernelGGL(buildx_kernel, dim3(B_), dim3(256), 0, stream, emb, caps, order, gate,
                       awe, x, t);
    // g = x @ w_ih^T + b_ih
    hipLaunchKernelGGL((gemm_kernel<true, 0, false, false>), dim3((4 * D_) / 64, 2), dim3(256),
                       0, stream, x, lstm_w_ih, lstm_b_ih, g, B_, 4 * D_, M_ + E_,
                       (const int*)nullptr, (long long)(4 * D_), 0LL, (const int*)nullptr, 0);
    // g += h @ w_hh^T + b_hh
    hipLaunchKernelGGL((gemm_kernel<true, 0, true, false>), dim3((4 * D_) / 64, 2), dim3(256),
                       0, stream, h, lstm_w_hh, lstm_b_hh, g, B_, 4 * D_, D_,
                       (const int*)nullptr, (long long)(4 * D_), 0LL, (const int*)nullptr, 0);
    // c,h update
    hipLaunchKernelGGL(lstm_ew_kernel, dim3((B_ * D_) / 256), dim3(256), 0, stream, g, h, c);
    // pred = h @ fc_w^T + fc_b  (masked, strided into output)
    hipLaunchKernelGGL((gemm_kernel<true, 0, false, true>), dim3((V_ + 63) / 64, 2), dim3(256),
                       0, stream, h, fc_w, fc_b, out, B_, V_, D_, (const int*)nullptr,
                       (long long)(T_ * V_), (long long)t * V_, declen, t);
  }
}

// Round 2
// 4752.443 us; speedup vs baseline: 2.2933x; 2.2933x over previous
//
#include <hip/hip_runtime.h>
#include <math.h>

#define B_ 128
#define P_ 196
#define E_ 2048
#define D_ 512
#define A_ 512
#define M_ 512
#define V_ 10000
#define L_ 21
#define T_ 20

// ---------------------------------------------------------------------------
// order kernel: stable argsort by descending caption length (B=128)
// also builds declen_sorted, encoder row map, and token rows for all (t,b)
// ---------------------------------------------------------------------------
__global__ void order_kernel(const int* __restrict__ lens, const int* __restrict__ caps,
                             int* __restrict__ order, int* __restrict__ declen,
                             int* __restrict__ row_map, int* __restrict__ tok_rows) {
  __shared__ int s_order[B_];
  int tid = threadIdx.x;
  if (tid < B_) {
    int li = lens[tid];
    int r = 0;
    for (int j = 0; j < B_; ++j) {
      int lj = lens[j];
      r += (lj > li) || (lj == li && j < tid);
    }
    s_order[r] = tid;
    declen[r] = li - 1;
  }
  __syncthreads();
  if (tid < B_) order[tid] = s_order[tid];
  for (int m = tid; m < B_ * P_; m += blockDim.x) {
    int b = m / P_, p = m - b * P_;
    row_map[m] = s_order[b] * P_ + p;
  }
  for (int i = tid; i < T_ * B_; i += blockDim.x) {
    int t = i >> 7, b = i & 127;
    tok_rows[i] = caps[s_order[b] * L_ + t];
  }
}

// ---------------------------------------------------------------------------
// mean over P of sorted encoder rows: mean[b,e]
// ---------------------------------------------------------------------------
__global__ void mean_kernel(const float* __restrict__ enc, const int* __restrict__ order,
                            float* __restrict__ mean) {
  int b = blockIdx.y;
  int e = blockIdx.x * blockDim.x + threadIdx.x;
  int ob = order[b];
  const float* base = enc + (long long)ob * P_ * E_ + e;
  float s = 0.f;
  for (int p = 0; p < P_; ++p) s += base[(long long)p * E_];
  mean[b * E_ + e] = s * (1.0f / P_);
}

// ---------------------------------------------------------------------------
// generic fp32 tiled GEMM: 64x64 tile, BK=16, 256 threads, 4x4 per thread.
// BT=false: C[m,n] = sum_k A[m,k] * B[k,n]   (B row-major [K,N], row stride bs)
// BT=true : C[m,n] = sum_k A[m,k] * B[n,k]   (B row-major [N,K], row stride bs)
// row_map: optional A-row indirection (A row stride = K).
// bias/bias2: optional per-n adds. xh_dup: also write v to xh_dup[m*2560+2048+n].
// CMAP==0: C[m*c_rstride + n].  CMAP==1: fc mapping b=m&127,t=m>>7 with mask.
// ---------------------------------------------------------------------------
template <bool BT, int ACT, int CMAP>
__global__ __launch_bounds__(256) void gemm_kernel(
    const float* __restrict__ A, const float* __restrict__ Bm,
    const float* __restrict__ bias, const float* __restrict__ bias2,
    float* __restrict__ C, int M, int N, int K, int bs,
    const int* __restrict__ row_map, long long c_rstride,
    float* __restrict__ xh_dup, const int* __restrict__ declen) {
  __shared__ float As[16][64];
  __shared__ float Bs[16][64];
  const int tid = threadIdx.x;
  const int bm = blockIdx.y * 64, bn = blockIdx.x * 64;
  const int tm = tid >> 4, tn = tid & 15;

  float acc[4][4];
#pragma unroll
  for (int i = 0; i < 4; ++i)
#pragma unroll
    for (int j = 0; j < 4; ++j) acc[i][j] = 0.f;

  const int lm = tid >> 2;        // 0..63
  const int lk = (tid & 3) * 4;   // 0,4,8,12

  for (int k0 = 0; k0 < K; k0 += 16) {
    {
      int m = bm + lm;
      float4 v = make_float4(0.f, 0.f, 0.f, 0.f);
      if (m < M) {
        int row = row_map ? row_map[m] : m;
        v = *(const float4*)(A + (long long)row * K + k0 + lk);
      }
      As[lk + 0][lm] = v.x;
      As[lk + 1][lm] = v.y;
      As[lk + 2][lm] = v.z;
      As[lk + 3][lm] = v.w;
    }
    if (!BT) {
      int k = tid >> 4;
      int n4 = (tid & 15) * 4;
      int n = bn + n4;
      float4 v = make_float4(0.f, 0.f, 0.f, 0.f);
      if (n < N) v = *(const float4*)(Bm + (long long)(k0 + k) * bs + n);
      Bs[k][n4 + 0] = v.x;
      Bs[k][n4 + 1] = v.y;
      Bs[k][n4 + 2] = v.z;
      Bs[k][n4 + 3] = v.w;
    } else {
      int n = bn + lm;
      float4 v = make_float4(0.f, 0.f, 0.f, 0.f);
      if (n < N) v = *(const float4*)(Bm + (long long)n * bs + k0 + lk);
      Bs[lk + 0][lm] = v.x;
      Bs[lk + 1][lm] = v.y;
      Bs[lk + 2][lm] = v.z;
      Bs[lk + 3][lm] = v.w;
    }
    __syncthreads();
#pragma unroll
    for (int k = 0; k < 16; ++k) {
      float a0 = As[k][tm * 4 + 0];
      float a1 = As[k][tm * 4 + 1];
      float a2 = As[k][tm * 4 + 2];
      float a3 = As[k][tm * 4 + 3];
      float b0 = Bs[k][tn * 4 + 0];
      float b1 = Bs[k][tn * 4 + 1];
      float b2 = Bs[k][tn * 4 + 2];
      float b3 = Bs[k][tn * 4 + 3];
      acc[0][0] += a0 * b0; acc[0][1] += a0 * b1; acc[0][2] += a0 * b2; acc[0][3] += a0 * b3;
      acc[1][0] += a1 * b0; acc[1][1] += a1 * b1; acc[1][2] += a1 * b2; acc[1][3] += a1 * b3;
      acc[2][0] += a2 * b0; acc[2][1] += a2 * b1; acc[2][2] += a2 * b2; acc[2][3] += a2 * b3;
      acc[3][0] += a3 * b0; acc[3][1] += a3 * b1; acc[3][2] += a3 * b2; acc[3][3] += a3 * b3;
    }
    __syncthreads();
  }

#pragma unroll
  for (int i = 0; i < 4; ++i) {
    int m = bm + tm * 4 + i;
    if (m >= M) continue;
#pragma unroll
    for (int j = 0; j < 4; ++j) {
      int n = bn + tn * 4 + j;
      if (n >= N) continue;
      float v = acc[i][j];
      if (bias) v += bias[n];
      if (bias2) v += bias2[n];
      if (ACT == 1) v = 1.f / (1.f + __expf(-v));
      if (CMAP == 0) {
        C[(long long)m * c_rstride + n] = v;
        if (xh_dup) xh_dup[m * 2560 + 2048 + n] = v;
      } else {
        int b = m & 127, t = m >> 7;
        bool active = t < declen[b];
        C[(long long)b * (T_ * V_) + (long long)t * V_ + n] = active ? v : 0.f;
      }
    }
  }
}

// ---------------------------------------------------------------------------
// step1: fused att2 + f_beta-gate GEMM.  A=h [128x512].
// N-space: [0,512) -> att2 = h@dec_att_w + b ; [512,2560) -> gate = sigmoid(h@f_beta_w + b)
// grid (40, 2)
// ---------------------------------------------------------------------------
__global__ __launch_bounds__(256) void step1_kernel(
    const float* __restrict__ h, const float* __restrict__ dec_att_w,
    const float* __restrict__ dec_att_b, const float* __restrict__ f_beta_w,
    const float* __restrict__ f_beta_b, float* __restrict__ att2,
    float* __restrict__ gate) {
  __shared__ float As[16][64];
  __shared__ float Bs[16][64];
  const int tid = threadIdx.x;
  const int bm = blockIdx.y * 64, bn = blockIdx.x * 64;
  const bool isatt = bn < 512;
  const float* Bp = isatt ? dec_att_w : f_beta_w;
  const int bstride = isatt ? 512 : 2048;
  const int ncol0 = isatt ? bn : bn - 512;
  const int tm = tid >> 4, tn = tid & 15;
  float acc[4][4];
#pragma unroll
  for (int i = 0; i < 4; ++i)
#pragma unroll
    for (int j = 0; j < 4; ++j) acc[i][j] = 0.f;
  const int lm = tid >> 2;
  const int lk = (tid & 3) * 4;
  for (int k0 = 0; k0 < 512; k0 += 16) {
    {
      int m = bm + lm;  // always < 128
      float4 v = *(const float4*)(h + m * 512 + k0 + lk);
      As[lk + 0][lm] = v.x;
      As[lk + 1][lm] = v.y;
      As[lk + 2][lm] = v.z;
      As[lk + 3][lm] = v.w;
    }
    {
      int k = tid >> 4;
      int n4 = (tid & 15) * 4;
      float4 v = *(const float4*)(Bp + (k0 + k) * bstride + ncol0 + n4);
      Bs[k][n4 + 0] = v.x;
      Bs[k][n4 + 1] = v.y;
      Bs[k][n4 + 2] = v.z;
      Bs[k][n4 + 3] = v.w;
    }
    __syncthreads();
#pragma unroll
    for (int k = 0; k < 16; ++k) {
      float a0 = As[k][tm * 4 + 0];
      float a1 = As[k][tm * 4 + 1];
      float a2 = As[k][tm * 4 + 2];
      float a3 = As[k][tm * 4 + 3];
      float b0 = Bs[k][tn * 4 + 0];
      float b1 = Bs[k][tn * 4 + 1];
      float b2 = Bs[k][tn * 4 + 2];
      float b3 = Bs[k][tn * 4 + 3];
      acc[0][0] += a0 * b0; acc[0][1] += a0 * b1; acc[0][2] += a0 * b2; acc[0][3] += a0 * b3;
      acc[1][0] += a1 * b0; acc[1][1] += a1 * b1; acc[1][2] += a1 * b2; acc[1][3] += a1 * b3;
      acc[2][0] += a2 * b0; acc[2][1] += a2 * b1; acc[2][2] += a2 * b2; acc[2][3] += a2 * b3;
      acc[3][0] += a3 * b0; acc[3][1] += a3 * b1; acc[3][2] += a3 * b2; acc[3][3] += a3 * b3;
    }
    __syncthreads();
  }
#pragma unroll
  for (int i = 0; i < 4; ++i) {
    int m = bm + tm * 4 + i;
#pragma unroll
    for (int j = 0; j < 4; ++j) {
      int nc = ncol0 + tn * 4 + j;
      float v = acc[i][j];
      if (isatt) {
        att2[m * 512 + nc] = v + dec_att_b[nc];
      } else {
        v += f_beta_b[nc];
        gate[m * 2048 + nc] = 1.f / (1.f + __expf(-v));
      }
    }
  }
}

// ---------------------------------------------------------------------------
// e + softmax + alpha: one block per batch row
// ---------------------------------------------------------------------------
__global__ __launch_bounds__(256) void esm_kernel(
    const float* __restrict__ att1, const float* __restrict__ att2,
    const float* __restrict__ w, const float* __restrict__ fb,
    const int* __restrict__ declen, int t,
    float* __restrict__ alpha_ws, float* __restrict__ alpha_out) {
  __shared__ float att2_s[A_];
  __shared__ float w_s[A_];
  __shared__ float e_s[P_];
  __shared__ float red[8];
  int b = blockIdx.x, tid = threadIdx.x;
  for (int i = tid; i < A_; i += 256) {
    att2_s[i] = att2[b * A_ + i];
    w_s[i] = w[i];
  }
  __syncthreads();
  int wave = tid >> 6, lane = tid & 63;
  for (int p = wave; p < P_; p += 4) {
    const float* row = att1 + ((long long)b * P_ + p) * A_;
    float s = 0.f;
#pragma unroll
    for (int i = 0; i < A_ / 64; ++i) {
      int idx = lane + i * 64;
      float v = row[idx] + att2_s[idx];
      s += (v > 0.f ? v : 0.f) * w_s[idx];
    }
    for (int off = 32; off; off >>= 1) s += __shfl_down(s, off);
    if (lane == 0) e_s[p] = s + fb[0];
  }
  __syncthreads();
  float m = -1e30f;
  for (int p = tid; p < P_; p += 256) m = fmaxf(m, e_s[p]);
  for (int off = 32; off; off >>= 1) m = fmaxf(m, __shfl_down(m, off));
  if (lane == 0) red[wave] = m;
  __syncthreads();
  m = fmaxf(fmaxf(red[0], red[1]), fmaxf(red[2], red[3]));
  float ssum = 0.f;
  for (int p = tid; p < P_; p += 256) {
    float ev = __expf(e_s[p] - m);
    e_s[p] = ev;
    ssum += ev;
  }
  for (int off = 32; off; off >>= 1) ssum += __shfl_down(ssum, off);
  if (lane == 0) red[4 + wave] = ssum;
  __syncthreads();
  ssum = red[4] + red[5] + red[6] + red[7];
  float inv = 1.f / ssum;
  bool active = (t < declen[b]);
  for (int p = tid; p < P_; p += 256) {
    float al = e_s[p] * inv;
    alpha_ws[b * P_ + p] = al;
    alpha_out[(long long)b * (T_ * P_) + t * P_ + p] = active ? al : 0.f;
  }
}

// ---------------------------------------------------------------------------
// awe: xh[b, e] = gate[b,e] * sum_p alpha[b,p] * enc[ob,p,e]
// grid (E/256, B), 256 threads
// ---------------------------------------------------------------------------
__global__ __launch_bounds__(256) void awe_kernel(
    const float* __restrict__ alpha_ws, const float* __restrict__ enc,
    const int* __restrict__ order, const float* __restrict__ gate,
    float* __restrict__ xh) {
  __shared__ float al[P_];
  int b = blockIdx.y;
  int e = blockIdx.x * 256 + threadIdx.x;
  for (int i = threadIdx.x; i < P_; i += 256) al[i] = alpha_ws[b * P_ + i];
  __syncthreads();
  int ob = order[b];
  const float* eb = enc + (long long)ob * P_ * E_ + e;
  float s = 0.f;
#pragma unroll 4
  for (int p = 0; p < P_; ++p) s += al[p] * eb[(long long)p * E_];
  xh[b * 2560 + e] = gate[b * 2048 + e] * s;
}

// ---------------------------------------------------------------------------
// gemm2: split-K GEMM for g2 = xh_awe @ W_ih[:,512:]^T + h @ W_hh^T
// A = xh [128 x 2560] = [gate*awe (2048) | h (512)]
// chunk z in 0..4: K rows z*512 .. z*512+511
// writes partials g_part[z][128][2048]; grid (32, 2, 5)
// ---------------------------------------------------------------------------
__global__ __launch_bounds__(256) void gemm2_kernel(
    const float* __restrict__ xh, const float* __restrict__ w_ih,
    const float* __restrict__ w_hh, float* __restrict__ g_part) {
  __shared__ float As[16][64];
  __shared__ float Bs[16][64];
  const int tid = threadIdx.x;
  const int bn = blockIdx.x * 64, bm = blockIdx.y * 64;
  const int z = blockIdx.z;
  const int tm = tid >> 4, tn = tid & 15;
  float acc[4][4];
#pragma unroll
  for (int i = 0; i < 4; ++i)
#pragma unroll
    for (int j = 0; j < 4; ++j) acc[i][j] = 0.f;
  const int lm = tid >> 2;
  const int lk = (tid & 3) * 4;
  const bool ih = (z < 4);
  for (int k0 = 0; k0 < 512; k0 += 16) {
    {
      int m = bm + lm;  // < 128
      float4 v = *(const float4*)(xh + m * 2560 + z * 512 + k0 + lk);
      As[lk + 0][lm] = v.x;
      As[lk + 1][lm] = v.y;
      As[lk + 2][lm] = v.z;
      As[lk + 3][lm] = v.w;
    }
    {
      int n = bn + lm;
      float4 v;
      if (ih)
        v = *(const float4*)(w_ih + (long long)n * 2560 + 512 + z * 512 + k0 + lk);
      else
        v = *(const float4*)(w_hh + (long long)n * 512 + k0 + lk);
      Bs[lk + 0][lm] = v.x;
      Bs[lk + 1][lm] = v.y;
      Bs[lk + 2][lm] = v.z;
      Bs[lk + 3][lm] = v.w;
    }
    __syncthreads();
#pragma unroll
    for (int k = 0; k < 16; ++k) {
      float a0 = As[k][tm * 4 + 0];
      float a1 = As[k][tm * 4 + 1];
      float a2 = As[k][tm * 4 + 2];
      float a3 = As[k][tm * 4 + 3];
      float b0 = Bs[k][tn * 4 + 0];
      float b1 = Bs[k][tn * 4 + 1];
      float b2 = Bs[k][tn * 4 + 2];
      float b3 = Bs[k][tn * 4 + 3];
      acc[0][0] += a0 * b0; acc[0][1] += a0 * b1; acc[0][2] += a0 * b2; acc[0][3] += a0 * b3;
      acc[1][0] += a1 * b0; acc[1][1] += a1 * b1; acc[1][2] += a1 * b2; acc[1][3] += a1 * b3;
      acc[2][0] += a2 * b0; acc[2][1] += a2 * b1; acc[2][2] += a2 * b2; acc[2][3] += a2 * b3;
      acc[3][0] += a3 * b0; acc[3][1] += a3 * b1; acc[3][2] += a3 * b2; acc[3][3] += a3 * b3;
    }
    __syncthreads();
  }
  float* gp = g_part + (long long)z * (128 * 2048);
#pragma unroll
  for (int i = 0; i < 4; ++i) {
    int m = bm + tm * 4 + i;
#pragma unroll
    for (int j = 0; j < 4; ++j) {
      int n = bn + tn * 4 + j;
      gp[m * 2048 + n] = acc[i][j];
    }
  }
}

// ---------------------------------------------------------------------------
// LSTM elementwise: g = g_emb + sum(partials) ; c,h update ; h -> h_next + xh tail
// ---------------------------------------------------------------------------
__global__ void lstm_ew_kernel(const float* __restrict__ g_emb,
                               const float* __restrict__ g_part,
                               float* __restrict__ c, float* __restrict__ h_next,
                               float* __restrict__ xh) {
  int idx = blockIdx.x * blockDim.x + threadIdx.x;  // b*512 + d
  int b = idx >> 9, d = idx & 511;
  int base = b * 2048 + d;
  float gi = g_emb[base], gf = g_emb[base + 512], gg = g_emb[base + 1024],
        go = g_emb[base + 1536];
#pragma unroll
  for (int z = 0; z < 5; ++z) {
    const float* gp = g_part + z * (128 * 2048) + base;
    gi += gp[0];
    gf += gp[512];
    gg += gp[1024];
    go += gp[1536];
  }
  float si = 1.f / (1.f + __expf(-gi));
  float sf = 1.f / (1.f + __expf(-gf));
  float so = 1.f / (1.f + __expf(-go));
  float cn = sf * c[idx] + si * tanhf(gg);
  float hn = so * tanhf(cn);
  c[idx] = cn;
  h_next[idx] = hn;
  xh[b * 2560 + 2048 + d] = hn;
}

// ---------------------------------------------------------------------------
// launch
// ---------------------------------------------------------------------------
extern "C" void kernel_launch(void* const* d_in, const int* in_sizes, int n_in,
                              void* d_out, int out_size, void* d_ws, size_t ws_size,
                              hipStream_t stream) {
  const float* enc       = (const float*)d_in[0];
  const int*   caps      = (const int*)d_in[1];
  const int*   lens      = (const int*)d_in[2];
  const float* emb       = (const float*)d_in[3];
  const float* enc_att_w = (const float*)d_in[4];
  const float* enc_att_b = (const float*)d_in[5];
  const float* dec_att_w = (const float*)d_in[6];
  const float* dec_att_b = (const float*)d_in[7];
  const float* full_att_w = (const float*)d_in[8];
  const float* full_att_b = (const float*)d_in[9];
  const float* init_h_w  = (const float*)d_in[10];
  const float* init_h_b  = (const float*)d_in[11];
  const float* init_c_w  = (const float*)d_in[12];
  const float* init_c_b  = (const float*)d_in[13];
  const float* f_beta_w  = (const float*)d_in[14];
  const float* f_beta_b  = (const float*)d_in[15];
  const float* lstm_w_ih = (const float*)d_in[16];
  const float* lstm_b_ih = (const float*)d_in[17];
  const float* lstm_w_hh = (const float*)d_in[18];
  const float* lstm_b_hh = (const float*)d_in[19];
  const float* fc_w      = (const float*)d_in[20];
  const float* fc_b      = (const float*)d_in[21];

  float* out = (float*)d_out;
  float* alphas_out = out + (long long)B_ * T_ * V_;

  // scratch living in the preds region of d_out (overwritten by fc at the end)
  float* g_all  = out;                       // 20*128*2048 = 5.24M floats
  float* g_part = out + 6 * 1024 * 1024;     // 5*128*2048 = 1.31M floats

  // workspace layout
  float* ws = (float*)d_ws;
  float* att1  = ws;                                // 25088*512
  float* mean  = att1 + (long long)B_ * P_ * A_;    // 128*2048
  float* h_all = mean + B_ * E_;                    // 21*128*512
  float* c     = h_all + (T_ + 1) * B_ * D_;        // 128*512
  float* att2  = c + B_ * D_;                       // 128*512
  float* gate  = att2 + B_ * A_;                    // 128*2048
  float* xh    = gate + B_ * E_;                    // 128*2560
  float* alpha_ws = xh + B_ * (M_ + E_);            // 128*196
  int* order   = (int*)(alpha_ws + B_ * P_);
  int* declen  = order + B_;
  int* row_map = declen + B_;                       // 25088
  int* tok_rows = row_map + B_ * P_;                // 2560

  // 1. sort + index maps
  hipLaunchKernelGGL(order_kernel, dim3(1), dim3(256), 0, stream, lens, caps, order, declen,
                     row_map, tok_rows);
  // 2. mean
  hipLaunchKernelGGL(mean_kernel, dim3(E_ / 256, B_), dim3(256), 0, stream, enc, order, mean);
  // 3/4. h0 (with xh-tail dup), c0
  hipLaunchKernelGGL((gemm_kernel<false, 0, 0>), dim3(D_ / 64, 2), dim3(256), 0, stream,
                     mean, init_h_w, init_h_b, (const float*)nullptr, h_all, B_, D_, E_, D_,
                     (const int*)nullptr, (long long)D_, xh, (const int*)nullptr);
  hipLaunchKernelGGL((gemm_kernel<false, 0, 0>), dim3(D_ / 64, 2), dim3(256), 0, stream,
                     mean, init_c_w, init_c_b, (const float*)nullptr, c, B_, D_, E_, D_,
                     (const int*)nullptr, (long long)D_, (float*)nullptr, (const int*)nullptr);
  // 5. att1 = enc_sorted @ enc_att_w + b
  hipLaunchKernelGGL((gemm_kernel<false, 0, 0>), dim3(A_ / 64, (B_ * P_) / 64), dim3(256), 0,
                     stream, enc, enc_att_w, enc_att_b, (const float*)nullptr, att1, B_ * P_,
                     A_, E_, A_, row_map, (long long)A_, (float*)nullptr, (const int*)nullptr);
  // 6. g_all[t*B+b] = emb(tok) @ W_ih[:, :512]^T + b_ih + b_hh  (batched over t)
  hipLaunchKernelGGL((gemm_kernel<true, 0, 0>), dim3(E_ / 64, (T_ * B_) / 64), dim3(256), 0,
                     stream, emb, lstm_w_ih, lstm_b_ih, lstm_b_hh, g_all, T_ * B_, 4 * D_, M_,
                     M_ + E_, tok_rows, (long long)(4 * D_), (float*)nullptr,
                     (const int*)nullptr);

  for (int t = 0; t < T_; ++t) {
    float* h_cur = h_all + (long long)t * B_ * D_;
    float* h_next = h_cur + B_ * D_;
    // att2 + gate (fused)
    hipLaunchKernelGGL(step1_kernel, dim3(40, 2), dim3(256), 0, stream, h_cur, dec_att_w,
                       dec_att_b, f_beta_w, f_beta_b, att2, gate);
    // e + softmax + alpha
    hipLaunchKernelGGL(esm_kernel, dim3(B_), dim3(256), 0, stream, att1, att2, full_att_w,
                       full_att_b, declen, t, alpha_ws, alphas_out);
    // awe (writes gate*awe into xh head)
    hipLaunchKernelGGL(awe_kernel, dim3(E_ / 256, B_), dim3(256), 0, stream, alpha_ws, enc,
                       order, gate, xh);
    // split-K lstm GEMM partials
    hipLaunchKernelGGL(gemm2_kernel, dim3(32, 2, 5), dim3(256), 0, stream, xh, lstm_w_ih,
                       lstm_w_hh, g_part);
    // LSTM elementwise
    hipLaunchKernelGGL(lstm_ew_kernel, dim3((B_ * D_) / 256), dim3(256), 0, stream,
                       g_all + (long long)t * B_ * (4 * D_), g_part, c, h_next, xh);
  }

  // 7. batched fc over all (t,b): preds (masked) — overwrites the scratch region
  hipLaunchKernelGGL((gemm_kernel<true, 0, 1>), dim3((V_ + 63) / 64, (T_ * B_) / 64),
                     dim3(256), 0, stream, h_all + B_ * D_, fc_w, fc_b, (const float*)nullptr,
                     out, T_ * B_, V_, D_, D_, (const int*)nullptr, 0LL, (float*)nullptr,
                     declen);
}